// Round 3
// baseline (83.969 us; speedup 1.0000x reference)
//
#include <hip/hip_runtime.h>

#define B_N 8
#define A_N 100000
#define M_N 64
#define ANCH 4
#define TPB 256
#define GX ((A_N + TPB * ANCH - 1) / (TPB * ANCH))   // 98 blocks per batch

// d_ws layout: [0, B_N*M_N) float4 transformed annotations {x1,x2,len,0},
// then ws_num[B_N*GX], ws_cnt[B_N*GX].

__global__ __launch_bounds__(512) void rl_prep(
    const float* __restrict__ annotations,   // (B, M, 3)
    float4* __restrict__ ann_t)
{
    const int t = threadIdx.x;               // 512 == B_N * M_N
    const float* p = annotations + t * 3;
    float x1 = p[0], x2 = p[1], lab = p[2];
    if (lab == -1.0f) { x1 = 1e30f; x2 = 1e30f; }
    // invalid => iw clamps to 0, len = 0, S = aw > 0, iou = 0 => never positive
    ann_t[t] = make_float4(x1, x2, x2 - x1, 0.0f);
}

__global__ __launch_bounds__(TPB) void rl_main(
    const float* __restrict__ regressions,   // (B, A, 2)
    const float* __restrict__ anchors,       // (1, A, 2)
    const float4* __restrict__ ann_t,        // (B*M) transformed
    float* __restrict__ ws_num, float* __restrict__ ws_cnt)
{
    __shared__ float4 ann_lds[M_N];          // for epilogue random access only
    const int b = blockIdx.y;
    const int tid = threadIdx.x;

    if (tid < M_N) ann_lds[tid] = ann_t[b * M_N + tid];
    __syncthreads();

    const int abase = blockIdx.x * (TPB * ANCH) + tid;

    float a0[ANCH], a1[ANCH], aw[ANCH], iwb[ANCH], Sb[ANCH];
    int idx[ANCH];
    bool act[ANCH];
    #pragma unroll
    for (int k = 0; k < ANCH; ++k) {
        const int a = abase + k * TPB;
        act[k] = (a < A_N);
        float2 anc = make_float2(0.0f, 1.0f);
        if (act[k]) anc = ((const float2*)anchors)[a];
        a0[k] = anc.x; a1[k] = anc.y; aw[k] = anc.y - anc.x;
        iwb[k] = -1.0f; Sb[k] = 1.0f; idx[k] = 0;   // encodes iou = -1
    }

    // Hot loop: wave-uniform reads of ann_t -> scalar loads; no LDS, no VMEM.
    // iou = iw/(S-iw), S = aw+len: monotone in (iw, -S), so compare
    // iw1*S2 > iw2*S1. Tournament pair (m, m+1) first to halve the carried
    // dep chain; strict '>' keeps the earlier index on ties at both levels.
    const float4* annb = ann_t + b * M_N;
    #pragma unroll 4
    for (int m = 0; m < M_N; m += 2) {
        const float4 t0 = annb[m];
        const float4 t1 = annb[m + 1];
        #pragma unroll
        for (int k = 0; k < ANCH; ++k) {
            const float iw0 = fmaxf(fminf(a1[k], t0.y) - fmaxf(a0[k], t0.x), 0.0f);
            const float iw1 = fmaxf(fminf(a1[k], t1.y) - fmaxf(a0[k], t1.x), 0.0f);
            const float S0 = aw[k] + t0.z;
            const float S1 = aw[k] + t1.z;
            const bool w1 = iw1 * S0 > iw0 * S1;       // tie -> m
            const float iww = w1 ? iw1 : iw0;
            const float Sw  = w1 ? S1  : S0;
            const int   mw  = w1 ? m + 1 : m;
            const bool better = iww * Sb[k] > iwb[k] * Sw;  // tie -> best
            iwb[k] = better ? iww : iwb[k];
            Sb[k]  = better ? Sw  : Sb[k];
            idx[k] = better ? mw  : idx[k];
        }
    }

    float lsum = 0.0f, lpos = 0.0f;
    #pragma unroll
    for (int k = 0; k < ANCH; ++k) {
        // exact gate, reference rounding order: ua = (aw+len) - iw
        const float ua  = fmaxf(Sb[k] - iwb[k], 1e-8f);
        const float iou = iwb[k] / ua;
        if (act[k] && iou >= 0.5f) {
            const float4 g = ann_lds[idx[k]];
            const float gw0 = g.z;
            const float gcx = g.x + 0.5f * gw0;
            const float gw  = fmaxf(gw0, 1.0f);
            const float acx = a0[k] + 0.5f * aw[k];
            const float tdx = ((gcx - acx) / aw[k]) / 0.1f;
            const float tdw = logf(gw / aw[k]) / 0.2f;
            const float2 rg =
                ((const float2*)regressions)[(size_t)b * A_N + abase + k * TPB];
            const float d0 = fabsf(tdx - rg.x);
            const float d1 = fabsf(tdw - rg.y);
            const float inv9 = 1.0f / 9.0f;
            const float s0 = (d0 <= inv9) ? 4.5f * d0 * d0 : d0 - 0.5f / 9.0f;
            const float s1 = (d1 <= inv9) ? 4.5f * d1 * d1 : d1 - 0.5f / 9.0f;
            lsum += s0 + s1;
            lpos += 1.0f;
        }
    }

    for (int o = 32; o > 0; o >>= 1) {
        lsum += __shfl_down(lsum, o, 64);
        lpos += __shfl_down(lpos, o, 64);
    }
    __shared__ float wsum[TPB / 64], wpos[TPB / 64];
    const int wid  = tid >> 6;
    const int lane = tid & 63;
    if (lane == 0) { wsum[wid] = lsum; wpos[wid] = lpos; }
    __syncthreads();
    if (tid == 0) {
        float s = 0.0f, p = 0.0f;
        #pragma unroll
        for (int w = 0; w < TPB / 64; ++w) { s += wsum[w]; p += wpos[w]; }
        const int slot = b * GX + blockIdx.x;
        ws_num[slot] = s;
        ws_cnt[slot] = p;
    }
}

__global__ __launch_bounds__(512) void rl_final(
    const float* __restrict__ ws_num,
    const float* __restrict__ ws_cnt,
    float* __restrict__ out)
{
    const int wid  = threadIdx.x >> 6;   // wave w handles batch w
    const int lane = threadIdx.x & 63;
    float s = 0.0f, c = 0.0f;
    for (int i = lane; i < GX; i += 64) {
        s += ws_num[wid * GX + i];
        c += ws_cnt[wid * GX + i];
    }
    for (int o = 32; o > 0; o >>= 1) {
        s += __shfl_down(s, o, 64);
        c += __shfl_down(c, o, 64);
    }
    __shared__ float pb[B_N];
    if (lane == 0) {
        const float cnt = 2.0f * c;
        pb[wid] = (cnt > 0.0f) ? s / fmaxf(cnt, 1.0f) : 0.0f;
    }
    __syncthreads();
    if (threadIdx.x == 0) {
        float acc = 0.0f;
        #pragma unroll
        for (int i = 0; i < B_N; ++i) acc += pb[i];
        out[0] = acc * (1.0f / (float)B_N);
    }
}

extern "C" void kernel_launch(void* const* d_in, const int* in_sizes, int n_in,
                              void* d_out, int out_size, void* d_ws, size_t ws_size,
                              hipStream_t stream) {
    const float* regressions = (const float*)d_in[0];
    const float* anchors     = (const float*)d_in[1];
    const float* annotations = (const float*)d_in[2];
    float* out = (float*)d_out;

    float4* ann_t = (float4*)d_ws;                       // [B_N*M_N]
    float*  ws_num = (float*)(ann_t + B_N * M_N);        // [B_N*GX]
    float*  ws_cnt = ws_num + B_N * GX;                  // [B_N*GX]

    rl_prep<<<1, 512, 0, stream>>>(annotations, ann_t);
    dim3 grid(GX, B_N);
    rl_main<<<grid, TPB, 0, stream>>>(regressions, anchors, ann_t,
                                      ws_num, ws_cnt);
    rl_final<<<1, 512, 0, stream>>>(ws_num, ws_cnt, out);
}